// Round 8
// baseline (89.447 us; speedup 1.0000x reference)
//
#include <hip/hip_runtime.h>
#include <math.h>

// Gaussian splatting forward renderer, MI355X — R7: 2 dispatches.
//  K1 gs_preprocess  : per-gaussian params + depth key -> ws; per-BLOCK key
//                      min / min-of-complement -> MMpart.
//  K2 gs_render_tile : 64 blocks (one per tile) x 1024 thr.
//      Phase 0: reduce MMpart -> identical dmin/dmax in every block.
//      Phase A: scan all N (coalesced), bbox survivors appended to one of
//               4 depth-range bucket lists in LDS.
//      Phase B: per-bucket rank sort (group b sorts bucket b; ~180 entries).
//      Phase C: 4 segment-groups (tid>>8) blend their bucket front-to-back,
//               uniform rounds, ballot early-out on negligible alpha.
//      Phase D: in-LDS ordered 4-way combine + white bkgd -> out.
// R2 lesson: fat-block cost was 55 bitonic barriers + 64x redundant
// divide-heavy preprocess — both absent here. R5 lesson: no device fences.
// Buckets are depth RANGES => concatenation == exact reference depth order.

#define NMAX 8192
#define TPB 256
#define RTPB 1024
#define NB 4
#define BCAP 768

__device__ __forceinline__ float keyToDepth(unsigned k) {
    unsigned bits = (k & 0x80000000u) ? (k & 0x7FFFFFFFu) : ~k;
    return __uint_as_float(bits);
}

__global__ __launch_bounds__(TPB) void gs_preprocess(
    const float* __restrict__ means3D, const float* __restrict__ opacity,
    const float* __restrict__ scales, const float* __restrict__ rotations,
    const float* __restrict__ shs, const float* __restrict__ viewmatrix,
    const float* __restrict__ projmatrix, const float* __restrict__ camcenter,
    float4* __restrict__ A, float4* __restrict__ B, float4* __restrict__ C,
    float4* __restrict__ D, unsigned* __restrict__ K,
    unsigned* __restrict__ MMpart, int N)
{
    const int tid = threadIdx.x;
    const int i = blockIdx.x * blockDim.x + tid;
    const bool valid = (i < N);

    unsigned kb = 0xFFFFFFFFu, nkb = 0xFFFFFFFFu;

    if (valid) {
        float V[16], P[16];
#pragma unroll
        for (int k = 0; k < 16; ++k) V[k] = viewmatrix[k];
#pragma unroll
        for (int k = 0; k < 16; ++k) P[k] = projmatrix[k];

        float mx = means3D[3*i+0], my = means3D[3*i+1], mz = means3D[3*i+2];

        float pv0 = mx*V[0] + my*V[4] + mz*V[8]  + V[12];
        float pv1 = mx*V[1] + my*V[5] + mz*V[9]  + V[13];
        float pv2 = mx*V[2] + my*V[6] + mz*V[10] + V[14];
        float pv3 = mx*V[3] + my*V[7] + mz*V[11] + V[15];

        float ph0 = pv0*P[0] + pv1*P[4] + pv2*P[8]  + pv3*P[12];
        float ph1 = pv0*P[1] + pv1*P[5] + pv2*P[9]  + pv3*P[13];
        float ph3 = pv0*P[3] + pv1*P[7] + pv2*P[11] + pv3*P[15];
        float invw = 1.0f / (ph3 + 1e-6f);
        float ppx = ph0 * invw, ppy = ph1 * invw;
        float depth = pv2;

        // SH deg 3, dirs = means3D - camera_center (unnormalized, per ref)
        float rdx = mx - camcenter[0], rdy = my - camcenter[1], rdz = mz - camcenter[2];
        float xx = rdx*rdx, yy = rdy*rdy, zz = rdz*rdz;
        float xy = rdx*rdy, yz = rdy*rdz, xz = rdx*rdz;
        const float C0 = 0.28209479177387814f;
        const float C1 = 0.4886025119029199f;
        const float C2_0 =  1.0925484305920792f, C2_1 = -1.0925484305920792f,
                    C2_2 =  0.31539156525252005f, C2_3 = -1.0925484305920792f,
                    C2_4 =  0.5462742152960396f;
        const float C3_0 = -0.5900435899266435f, C3_1 = 2.890611442640554f,
                    C3_2 = -0.4570457994644658f, C3_3 = 0.3731763325901154f,
                    C3_4 = -0.4570457994644658f, C3_5 = 1.445305721320277f,
                    C3_6 = -0.5900435899266435f;
        float col[3];
#pragma unroll
        for (int c = 0; c < 3; ++c) {
            const float* sh = shs + (size_t)i*48 + c;
            float res = C0*sh[0]
                - C1*rdy*sh[3] + C1*rdz*sh[6] - C1*rdx*sh[9]
                + C2_0*xy*sh[12] + C2_1*yz*sh[15] + C2_2*(2.f*zz-xx-yy)*sh[18]
                + C2_3*xz*sh[21] + C2_4*(xx-yy)*sh[24]
                + C3_0*rdy*(3.f*xx-yy)*sh[27] + C3_1*xy*rdz*sh[30]
                + C3_2*rdy*(4.f*zz-xx-yy)*sh[33] + C3_3*rdz*(2.f*zz-3.f*xx-3.f*yy)*sh[36]
                + C3_4*rdx*(4.f*zz-xx-yy)*sh[39] + C3_5*rdz*(xx-yy)*sh[42]
                + C3_6*rdx*(xx-3.f*yy)*sh[45];
            col[c] = fmaxf(res + 0.5f, 0.0f);
        }

        // cov3d
        float qr = rotations[4*i+0], qx = rotations[4*i+1], qy = rotations[4*i+2], qz = rotations[4*i+3];
        float qn = sqrtf(qr*qr + qx*qx + qy*qy + qz*qz);
        qr /= qn; qx /= qn; qy /= qn; qz /= qn;
        float R00 = 1.f - 2.f*(qy*qy + qz*qz), R01 = 2.f*(qx*qy - qr*qz), R02 = 2.f*(qx*qz + qr*qy);
        float R10 = 2.f*(qx*qy + qr*qz), R11 = 1.f - 2.f*(qx*qx + qz*qz), R12 = 2.f*(qy*qz - qr*qx);
        float R20 = 2.f*(qx*qz - qr*qy), R21 = 2.f*(qy*qz + qr*qx), R22 = 1.f - 2.f*(qx*qx + qy*qy);
        float s0 = scales[3*i+0], s1 = scales[3*i+1], s2 = scales[3*i+2];
        float L00=R00*s0, L01=R01*s1, L02=R02*s2;
        float L10=R10*s0, L11=R11*s1, L12=R12*s2;
        float L20=R20*s0, L21=R21*s1, L22=R22*s2;
        float c300=L00*L00+L01*L01+L02*L02;
        float c301=L00*L10+L01*L11+L02*L12;
        float c302=L00*L20+L01*L21+L02*L22;
        float c311=L10*L10+L11*L11+L12*L12;
        float c312=L10*L20+L11*L21+L12*L22;
        float c322=L20*L20+L21*L21+L22*L22;

        // EWA projection
        const float TANX = 0.5773502691896257f;
        const float FX = 128.0f / (2.0f * TANX);
        float tz = pv2;
        float limx = 1.3f * TANX;
        float txv = fminf(fmaxf(pv0 / tz, -limx), limx) * tz;
        float tyv = fminf(fmaxf(pv1 / tz, -limx), limx) * tz;
        float j00 = FX / tz, j02 = -txv * FX / (tz*tz);
        float j11 = FX / tz, j12 = -tyv * FX / (tz*tz);

        float Wm00=V[0], Wm01=V[4], Wm02=V[8];
        float Wm10=V[1], Wm11=V[5], Wm12=V[9];
        float Wm20=V[2], Wm21=V[6], Wm22=V[10];

        float t00 = Wm00*c300 + Wm01*c301 + Wm02*c302;
        float t01 = Wm00*c301 + Wm01*c311 + Wm02*c312;
        float t02 = Wm00*c302 + Wm01*c312 + Wm02*c322;
        float t10 = Wm10*c300 + Wm11*c301 + Wm12*c302;
        float t11 = Wm10*c301 + Wm11*c311 + Wm12*c312;
        float t12 = Wm10*c302 + Wm11*c312 + Wm12*c322;
        float t20 = Wm20*c300 + Wm21*c301 + Wm22*c302;
        float t21 = Wm20*c301 + Wm21*c311 + Wm22*c312;
        float t22 = Wm20*c302 + Wm21*c312 + Wm22*c322;
        float M00 = t00*Wm00 + t01*Wm01 + t02*Wm02;
        float M01 = t00*Wm10 + t01*Wm11 + t02*Wm12;
        float M02 = t00*Wm20 + t01*Wm21 + t02*Wm22;
        float M11 = t10*Wm10 + t11*Wm11 + t12*Wm12;
        float M12 = t10*Wm20 + t11*Wm21 + t12*Wm22;
        float M21 = t20*Wm10 + t21*Wm11 + t22*Wm12;
        float M20 = t20*Wm00 + t21*Wm01 + t22*Wm02;
        float M22 = t20*Wm20 + t21*Wm21 + t22*Wm22;

        float JM00 = j00*M00 + j02*M20;
        float JM01 = j00*M01 + j02*M21;
        float JM02 = j00*M02 + j02*M22;
        float JM11 = j11*M11 + j12*M21;
        float JM12 = j11*M12 + j12*M22;
        float a = JM00*j00 + JM02*j02 + 0.3f;
        float b = JM01*j11 + JM02*j12;
        float d = JM11*j11 + JM12*j12 + 0.3f;

        float m2x = ((ppx + 1.0f)*128.0f - 1.0f)*0.5f;
        float m2y = ((ppy + 1.0f)*128.0f - 1.0f)*0.5f;

        float det = a*d - b*b;
        float mid = 0.5f*(a + d);
        float sq = sqrtf(fmaxf(mid*mid - det, 0.1f));
        float radii = 3.0f * ceilf(sqrtf(fmaxf(mid + sq, mid - sq)));
        float rminx = fminf(fmaxf(m2x - radii, 0.0f), 127.0f);
        float rminy = fminf(fmaxf(m2y - radii, 0.0f), 127.0f);
        float rmaxx = fminf(fmaxf(m2x + radii, 0.0f), 127.0f);
        float rmaxy = fminf(fmaxf(m2y + radii, 0.0f), 127.0f);

        float idet = 1.0f / det;
        float c00i = d*idet, c11i = a*idet, cxyi = -2.0f*b*idet;

        kb = __float_as_uint(depth);
        kb = (kb & 0x80000000u) ? ~kb : (kb | 0x80000000u);
        nkb = ~kb;

        K[i] = kb;
        A[i] = make_float4(m2x, m2y, c00i, c11i);
        B[i] = make_float4(cxyi, opacity[i], depth, 0.0f);
        C[i] = make_float4(col[0], col[1], col[2], 0.0f);
        D[i] = make_float4(rminx, rminy, rmaxx, rmaxy);
    }

    __shared__ unsigned s_r0[TPB], s_r1[TPB];
    s_r0[tid] = kb; s_r1[tid] = nkb;
    __syncthreads();
    for (int off = TPB/2; off > 0; off >>= 1) {
        if (tid < off) {
            s_r0[tid] = min(s_r0[tid], s_r0[tid + off]);
            s_r1[tid] = min(s_r1[tid], s_r1[tid + off]);
        }
        __syncthreads();
    }
    if (tid == 0) {
        MMpart[2*blockIdx.x]   = s_r0[0];
        MMpart[2*blockIdx.x+1] = s_r1[0];
    }
}

// 64 blocks (one per tile) x 1024 thr: scan + bucket + sort + blend + combine.
__global__ __launch_bounds__(RTPB) void gs_render_tile(
    const float4* __restrict__ A, const float4* __restrict__ B,
    const float4* __restrict__ C, const float4* __restrict__ D,
    const unsigned* __restrict__ K, const unsigned* __restrict__ MMpart,
    float* __restrict__ out, int N, int nblk)
{
    __shared__ unsigned long long s_keys[NB][BCAP];   // 24 KiB
    __shared__ unsigned s_sorted[NB][BCAP];           // 12 KiB
    __shared__ int s_cnt[NB];
    __shared__ float4 sA[NB][256], sB[NB][256], sC[NB][256]; // 48 KiB
    __shared__ float s_part[NB][256][6];              // 24 KiB

    const int tid = threadIdx.x;
    const int tile = blockIdx.x;
    const int h = (tile >> 3) * 16;
    const int w = (tile & 7) * 16;
    const float fw = (float)w, fh = (float)h;

    // Phase 0: global dmin/dmax (identical in every block, order-independent)
    unsigned kmin = 0xFFFFFFFFu, nkmin = 0xFFFFFFFFu;
    for (int bidx = 0; bidx < nblk; ++bidx) {
        kmin  = min(kmin,  MMpart[2*bidx]);
        nkmin = min(nkmin, MMpart[2*bidx+1]);
    }
    const float dmin = keyToDepth(kmin);
    const float dmax = keyToDepth(~nkmin);
    const float scale = (float)NB / fmaxf(dmax - dmin, 1e-20f);

    if (tid < NB) s_cnt[tid] = 0;
    __syncthreads();

    // Phase A: scan all N, append survivors to depth-range bucket lists
    for (int g = tid; g < N; g += RTPB) {
        float4 d4 = D[g];
        float tlx = fmaxf(d4.x, fw), tly = fmaxf(d4.y, fh);
        float brx = fminf(d4.z, fw + 15.0f), bry = fminf(d4.w, fh + 15.0f);
        if (brx > tlx && bry > tly) {
            unsigned kb = K[g];
            float depth = keyToDepth(kb);
            int sg = (int)((depth - dmin) * scale);
            sg = sg < 0 ? 0 : (sg > NB-1 ? NB-1 : sg);
            int pos = atomicAdd(&s_cnt[sg], 1);
            if (pos < BCAP)
                s_keys[sg][pos] = (((unsigned long long)kb) << 32) | (unsigned)g;
        }
    }
    __syncthreads();

    const int b = tid >> 8;        // segment group == depth bucket
    const int p = tid & 255;       // pixel within tile
    int cb = min(s_cnt[b], BCAP);
    // uniform rounds across the block (barrier safety)
    int maxcb = max(max(min(s_cnt[0],BCAP), min(s_cnt[1],BCAP)),
                    max(min(s_cnt[2],BCAP), min(s_cnt[3],BCAP)));

    // Phase B: rank sort bucket b (unique composite keys => permutation)
    for (int s = p; s < cb; s += 256) {
        unsigned long long my = s_keys[b][s];
        int r = 0;
        for (int j = 0; j < cb; ++j) r += (s_keys[b][j] < my);
        s_sorted[b][r] = (unsigned)(my & 0xffffffffu);
    }
    __syncthreads();

    // Phase C: blend (uniform round count; ballot early-out)
    const int pxi = p & 15, pyi = p >> 4;
    const float px = (float)(w + pxi), py = (float)(h + pyi);
    float T = 1.0f, acR = 0.f, acG = 0.f, acB = 0.f, acD = 0.f, acA = 0.f;

    const int rounds = (maxcb + 255) >> 8;
    for (int r = 0; r < rounds; ++r) {
        int base = r << 8;
        int m = cb - base; m = m < 0 ? 0 : (m > 256 ? 256 : m);
        if (r) __syncthreads();
        if (p < m) {
            int g = (int)s_sorted[b][base + p];
            sA[b][p] = A[g]; sB[b][p] = B[g]; sC[b][p] = C[g];
        }
        __syncthreads();
#pragma unroll 2
        for (int jj = 0; jj < m; ++jj) {
            float4 a4 = sA[b][jj];
            float ddx = px - a4.x, ddy = py - a4.y;
            float4 b4 = sB[b][jj];
            float power = -0.5f * (ddx*ddx*a4.z + ddy*ddy*a4.w + ddx*ddy*b4.x);
            if (__any(power > -14.0f)) {   // skipped terms: alpha < 1e-6
                float4 c4 = sC[b][jj];
                float alpha = fminf(__expf(power) * b4.y, 0.99f);
                float wgt = alpha * T;
                acR += wgt * c4.x; acG += wgt * c4.y; acB += wgt * c4.z;
                acD += wgt * b4.z; acA += wgt;
                T *= (1.0f - alpha);
            }
        }
    }

    // Phase D: ordered 4-way combine + white background
    __syncthreads();
    s_part[b][p][0] = acR; s_part[b][p][1] = acG; s_part[b][p][2] = acB;
    s_part[b][p][3] = acD; s_part[b][p][4] = acA; s_part[b][p][5] = T;
    __syncthreads();
    if (b == 0) {
        float Tpre = 1.0f, CR = 0.f, CG = 0.f, CB = 0.f, DP = 0.f, AC = 0.f;
#pragma unroll
        for (int s = 0; s < NB; ++s) {
            CR += Tpre * s_part[s][p][0];
            CG += Tpre * s_part[s][p][1];
            CB += Tpre * s_part[s][p][2];
            DP += Tpre * s_part[s][p][3];
            AC += Tpre * s_part[s][p][4];
            Tpre *= s_part[s][p][5];
        }
        CR += (1.0f - AC); CG += (1.0f - AC); CB += (1.0f - AC);

        const int y = h + pyi, x = w + pxi;
        const int pix = y * 128 + x;
        out[pix*3 + 0] = CR;
        out[pix*3 + 1] = CG;
        out[pix*3 + 2] = CB;
        out[128*128*3 + pix] = DP;
        out[128*128*3 + 128*128 + pix] = AC;
    }
}

extern "C" void kernel_launch(void* const* d_in, const int* in_sizes, int n_in,
                              void* d_out, int out_size, void* d_ws, size_t ws_size,
                              hipStream_t stream) {
    const float* means3D    = (const float*)d_in[0];
    const float* opacity    = (const float*)d_in[1];
    const float* scales     = (const float*)d_in[2];
    const float* rotations  = (const float*)d_in[3];
    const float* shs        = (const float*)d_in[4];
    const float* viewmatrix = (const float*)d_in[5];
    const float* projmatrix = (const float*)d_in[6];
    const float* camcenter  = (const float*)d_in[7];
    float* out = (float*)d_out;

    int N = in_sizes[0] / 3;   // 8192
    int nblk = (N + TPB - 1) / TPB;

    char* p = (char*)d_ws;
    float4* A = (float4*)p;          p += (size_t)NMAX * sizeof(float4);
    float4* B = (float4*)p;          p += (size_t)NMAX * sizeof(float4);
    float4* C = (float4*)p;          p += (size_t)NMAX * sizeof(float4);
    float4* D = (float4*)p;          p += (size_t)NMAX * sizeof(float4);
    unsigned* K = (unsigned*)p;      p += (size_t)NMAX * sizeof(unsigned);
    unsigned* MMpart = (unsigned*)p; p += (size_t)2 * nblk * sizeof(unsigned);

    gs_preprocess<<<nblk, TPB, 0, stream>>>(
        means3D, opacity, scales, rotations, shs, viewmatrix, projmatrix,
        camcenter, A, B, C, D, K, MMpart, N);

    gs_render_tile<<<64, RTPB, 0, stream>>>(
        A, B, C, D, K, MMpart, out, N, nblk);
}

// Round 9
// 40.277 us; speedup vs baseline: 2.2208x; 2.2208x over previous
//
#include <hip/hip_runtime.h>
#include <hip/hip_fp16.h>
#include <math.h>

// Gaussian splatting forward renderer, MI355X — R8: 3 lean nodes.
//  K1 gs_preprocess : per-gaussian A=(m2x,m2y,c00,c11), Bp=(cxy,op,rgb+depth
//                     packed f16), TMK=(tilemask u64, depth key) -> ws;
//                     per-block key min/max -> MMpart.
//  K2 gs_render     : grid (4 macro-buckets x 64 tiles) x 1024 thr, 16 depth
//                     slices total (4 sub-slices per block, tid>>8 = group).
//                     Scan N via tilemask bit (1 x b128/gaussian), bucket by
//                     depth slice, rank-sort per slice, blend 2 x b128/gauss,
//                     in-block ordered 4-slice combine -> macro partials.
//  K3 gs_combine    : ordered combine of 4 macro-buckets + white bkgd.
// Lessons baked in: work/CU is the invariant for the LDS-broadcast blend
// (R7); node gap ~4.6us (R7); no device fences (R5); no redundant
// preprocess (R2). Slices are depth RANGES => exact reference order.

#define NMAX 8192
#define TPB 256
#define RTPB 1024
#define NMAC 4
#define NSUB 4
#define NSLICE 16
#define CAP 384

__device__ __forceinline__ float keyToDepth(unsigned k) {
    unsigned bits = (k & 0x80000000u) ? (k & 0x7FFFFFFFu) : ~k;
    return __uint_as_float(bits);
}

__global__ __launch_bounds__(TPB) void gs_preprocess(
    const float* __restrict__ means3D, const float* __restrict__ opacity,
    const float* __restrict__ scales, const float* __restrict__ rotations,
    const float* __restrict__ shs, const float* __restrict__ viewmatrix,
    const float* __restrict__ projmatrix, const float* __restrict__ camcenter,
    float4* __restrict__ A, float4* __restrict__ Bp, uint4* __restrict__ TMK,
    unsigned* __restrict__ MMpart, int N)
{
    const int tid = threadIdx.x;
    const int i = blockIdx.x * blockDim.x + tid;
    const bool valid = (i < N);

    unsigned kb = 0xFFFFFFFFu, nkb = 0xFFFFFFFFu;

    if (valid) {
        float V[16], P[16];
#pragma unroll
        for (int k = 0; k < 16; ++k) V[k] = viewmatrix[k];
#pragma unroll
        for (int k = 0; k < 16; ++k) P[k] = projmatrix[k];

        float mx = means3D[3*i+0], my = means3D[3*i+1], mz = means3D[3*i+2];

        float pv0 = mx*V[0] + my*V[4] + mz*V[8]  + V[12];
        float pv1 = mx*V[1] + my*V[5] + mz*V[9]  + V[13];
        float pv2 = mx*V[2] + my*V[6] + mz*V[10] + V[14];
        float pv3 = mx*V[3] + my*V[7] + mz*V[11] + V[15];

        float ph0 = pv0*P[0] + pv1*P[4] + pv2*P[8]  + pv3*P[12];
        float ph1 = pv0*P[1] + pv1*P[5] + pv2*P[9]  + pv3*P[13];
        float ph3 = pv0*P[3] + pv1*P[7] + pv2*P[11] + pv3*P[15];
        float invw = 1.0f / (ph3 + 1e-6f);
        float ppx = ph0 * invw, ppy = ph1 * invw;
        float depth = pv2;

        // SH deg 3, dirs = means3D - camera_center (unnormalized, per ref)
        float rdx = mx - camcenter[0], rdy = my - camcenter[1], rdz = mz - camcenter[2];
        float xx = rdx*rdx, yy = rdy*rdy, zz = rdz*rdz;
        float xy = rdx*rdy, yz = rdy*rdz, xz = rdx*rdz;
        const float C0 = 0.28209479177387814f;
        const float C1 = 0.4886025119029199f;
        const float C2_0 =  1.0925484305920792f, C2_1 = -1.0925484305920792f,
                    C2_2 =  0.31539156525252005f, C2_3 = -1.0925484305920792f,
                    C2_4 =  0.5462742152960396f;
        const float C3_0 = -0.5900435899266435f, C3_1 = 2.890611442640554f,
                    C3_2 = -0.4570457994644658f, C3_3 = 0.3731763325901154f,
                    C3_4 = -0.4570457994644658f, C3_5 = 1.445305721320277f,
                    C3_6 = -0.5900435899266435f;
        float col[3];
#pragma unroll
        for (int c = 0; c < 3; ++c) {
            const float* sh = shs + (size_t)i*48 + c;
            float res = C0*sh[0]
                - C1*rdy*sh[3] + C1*rdz*sh[6] - C1*rdx*sh[9]
                + C2_0*xy*sh[12] + C2_1*yz*sh[15] + C2_2*(2.f*zz-xx-yy)*sh[18]
                + C2_3*xz*sh[21] + C2_4*(xx-yy)*sh[24]
                + C3_0*rdy*(3.f*xx-yy)*sh[27] + C3_1*xy*rdz*sh[30]
                + C3_2*rdy*(4.f*zz-xx-yy)*sh[33] + C3_3*rdz*(2.f*zz-3.f*xx-3.f*yy)*sh[36]
                + C3_4*rdx*(4.f*zz-xx-yy)*sh[39] + C3_5*rdz*(xx-yy)*sh[42]
                + C3_6*rdx*(xx-3.f*yy)*sh[45];
            col[c] = fmaxf(res + 0.5f, 0.0f);
        }

        // cov3d
        float qr = rotations[4*i+0], qx = rotations[4*i+1], qy = rotations[4*i+2], qz = rotations[4*i+3];
        float qn = sqrtf(qr*qr + qx*qx + qy*qy + qz*qz);
        qr /= qn; qx /= qn; qy /= qn; qz /= qn;
        float R00 = 1.f - 2.f*(qy*qy + qz*qz), R01 = 2.f*(qx*qy - qr*qz), R02 = 2.f*(qx*qz + qr*qy);
        float R10 = 2.f*(qx*qy + qr*qz), R11 = 1.f - 2.f*(qx*qx + qz*qz), R12 = 2.f*(qy*qz - qr*qx);
        float R20 = 2.f*(qx*qz - qr*qy), R21 = 2.f*(qy*qz + qr*qx), R22 = 1.f - 2.f*(qx*qx + qy*qy);
        float s0 = scales[3*i+0], s1 = scales[3*i+1], s2 = scales[3*i+2];
        float L00=R00*s0, L01=R01*s1, L02=R02*s2;
        float L10=R10*s0, L11=R11*s1, L12=R12*s2;
        float L20=R20*s0, L21=R21*s1, L22=R22*s2;
        float c300=L00*L00+L01*L01+L02*L02;
        float c301=L00*L10+L01*L11+L02*L12;
        float c302=L00*L20+L01*L21+L02*L22;
        float c311=L10*L10+L11*L11+L12*L12;
        float c312=L10*L20+L11*L21+L12*L22;
        float c322=L20*L20+L21*L21+L22*L22;

        // EWA projection
        const float TANX = 0.5773502691896257f;
        const float FX = 128.0f / (2.0f * TANX);
        float tz = pv2;
        float limx = 1.3f * TANX;
        float txv = fminf(fmaxf(pv0 / tz, -limx), limx) * tz;
        float tyv = fminf(fmaxf(pv1 / tz, -limx), limx) * tz;
        float j00 = FX / tz, j02 = -txv * FX / (tz*tz);
        float j11 = FX / tz, j12 = -tyv * FX / (tz*tz);

        float Wm00=V[0], Wm01=V[4], Wm02=V[8];
        float Wm10=V[1], Wm11=V[5], Wm12=V[9];
        float Wm20=V[2], Wm21=V[6], Wm22=V[10];

        float t00 = Wm00*c300 + Wm01*c301 + Wm02*c302;
        float t01 = Wm00*c301 + Wm01*c311 + Wm02*c312;
        float t02 = Wm00*c302 + Wm01*c312 + Wm02*c322;
        float t10 = Wm10*c300 + Wm11*c301 + Wm12*c302;
        float t11 = Wm10*c301 + Wm11*c311 + Wm12*c312;
        float t12 = Wm10*c302 + Wm11*c312 + Wm12*c322;
        float t20 = Wm20*c300 + Wm21*c301 + Wm22*c302;
        float t21 = Wm20*c301 + Wm21*c311 + Wm22*c312;
        float t22 = Wm20*c302 + Wm21*c312 + Wm22*c322;
        float M00 = t00*Wm00 + t01*Wm01 + t02*Wm02;
        float M01 = t00*Wm10 + t01*Wm11 + t02*Wm12;
        float M02 = t00*Wm20 + t01*Wm21 + t02*Wm22;
        float M11 = t10*Wm10 + t11*Wm11 + t12*Wm12;
        float M12 = t10*Wm20 + t11*Wm21 + t12*Wm22;
        float M21 = t20*Wm10 + t21*Wm11 + t22*Wm12;
        float M20 = t20*Wm00 + t21*Wm01 + t22*Wm02;
        float M22 = t20*Wm20 + t21*Wm21 + t22*Wm22;

        float JM00 = j00*M00 + j02*M20;
        float JM01 = j00*M01 + j02*M21;
        float JM02 = j00*M02 + j02*M22;
        float JM11 = j11*M11 + j12*M21;
        float JM12 = j11*M12 + j12*M22;
        float a = JM00*j00 + JM02*j02 + 0.3f;
        float b = JM01*j11 + JM02*j12;
        float d = JM11*j11 + JM12*j12 + 0.3f;

        float m2x = ((ppx + 1.0f)*128.0f - 1.0f)*0.5f;
        float m2y = ((ppy + 1.0f)*128.0f - 1.0f)*0.5f;

        float det = a*d - b*b;
        float mid = 0.5f*(a + d);
        float sq = sqrtf(fmaxf(mid*mid - det, 0.1f));
        float radii = 3.0f * ceilf(sqrtf(fmaxf(mid + sq, mid - sq)));
        float rminx = fminf(fmaxf(m2x - radii, 0.0f), 127.0f);
        float rminy = fminf(fmaxf(m2y - radii, 0.0f), 127.0f);
        float rmaxx = fminf(fmaxf(m2x + radii, 0.0f), 127.0f);
        float rmaxy = fminf(fmaxf(m2y + radii, 0.0f), 127.0f);

        float idet = 1.0f / det;
        float c00i = d*idet, c11i = a*idet, cxyi = -2.0f*b*idet;

        // exact per-tile overlap mask (factorized; float tests == ref in_mask)
        unsigned colmask = 0, rowmask = 0;
#pragma unroll
        for (int c = 0; c < 8; ++c) {
            float wc = 16.0f * c;
            if (fminf(rmaxx, wc + 15.0f) > fmaxf(rminx, wc)) colmask |= 1u << c;
            if (fminf(rmaxy, wc + 15.0f) > fmaxf(rminy, wc)) rowmask |= 1u << c;
        }
        unsigned long long mask = 0;
#pragma unroll
        for (int r = 0; r < 8; ++r)
            if ((rowmask >> r) & 1) mask |= ((unsigned long long)colmask) << (8*r);

        kb = __float_as_uint(depth);
        kb = (kb & 0x80000000u) ? ~kb : (kb | 0x80000000u);
        nkb = ~kb;

        // pack rgb + depth as f16 (abs err <~4e-3 vs 0.255 threshold)
        unsigned rg = ((unsigned)__half_as_ushort(__float2half(col[1])) << 16)
                    |  (unsigned)__half_as_ushort(__float2half(col[0]));
        unsigned bd = ((unsigned)__half_as_ushort(__float2half(depth)) << 16)
                    |  (unsigned)__half_as_ushort(__float2half(col[2]));

        A[i]   = make_float4(m2x, m2y, c00i, c11i);
        Bp[i]  = make_float4(cxyi, opacity[i], __uint_as_float(rg), __uint_as_float(bd));
        TMK[i] = make_uint4((unsigned)mask, (unsigned)(mask >> 32), kb, 0u);
    }

    __shared__ unsigned s_r0[TPB], s_r1[TPB];
    s_r0[tid] = kb; s_r1[tid] = nkb;
    __syncthreads();
    for (int off = TPB/2; off > 0; off >>= 1) {
        if (tid < off) {
            s_r0[tid] = min(s_r0[tid], s_r0[tid + off]);
            s_r1[tid] = min(s_r1[tid], s_r1[tid + off]);
        }
        __syncthreads();
    }
    if (tid == 0) {
        MMpart[2*blockIdx.x]   = s_r0[0];
        MMpart[2*blockIdx.x+1] = s_r1[0];
    }
}

// grid (NMAC macro-buckets, 64 tiles) x 1024 thr
__global__ __launch_bounds__(RTPB) void gs_render(
    const float4* __restrict__ A, const float4* __restrict__ Bp,
    const uint4* __restrict__ TMK, const unsigned* __restrict__ MMpart,
    float4* __restrict__ P1, float2* __restrict__ P2, int N, int nblk)
{
    __shared__ unsigned long long s_keys[NSUB][CAP];  // 12 KiB
    __shared__ unsigned s_sorted[NSUB][CAP];          // 6 KiB
    __shared__ int s_cnt[NSUB];
    __shared__ float4 sA[NSUB][256], sBp[NSUB][256];  // 32 KiB
    __shared__ float s_part[NSUB][256][6];            // 24 KiB

    const int tid = threadIdx.x;
    const int mac = blockIdx.x;
    const int tile = blockIdx.y;
    const int h = (tile >> 3) * 16;
    const int w = (tile & 7) * 16;

    // Phase 0: global dmin/dmax (identical in every block, order-independent)
    unsigned kmin = 0xFFFFFFFFu, nkmin = 0xFFFFFFFFu;
    for (int bidx = 0; bidx < nblk; ++bidx) {
        kmin  = min(kmin,  MMpart[2*bidx]);
        nkmin = min(nkmin, MMpart[2*bidx+1]);
    }
    const float dmin = keyToDepth(kmin);
    const float dmax = keyToDepth(~nkmin);
    const float scale = (float)NSLICE / fmaxf(dmax - dmin, 1e-20f);

    if (tid < NSUB) s_cnt[tid] = 0;
    __syncthreads();

    // Phase A: masked scan; append survivors of this macro's 4 slices
    for (int g = tid; g < N; g += RTPB) {
        uint4 t4 = TMK[g];
        unsigned long long mask = (unsigned long long)t4.x
                                | ((unsigned long long)t4.y << 32);
        if ((mask >> tile) & 1ull) {
            unsigned kb = t4.z;
            float depth = keyToDepth(kb);
            int sg = (int)((depth - dmin) * scale);
            sg = sg < 0 ? 0 : (sg > NSLICE-1 ? NSLICE-1 : sg);
            if ((sg >> 2) == mac) {
                int sub = sg & 3;
                int pos = atomicAdd(&s_cnt[sub], 1);
                if (pos < CAP)
                    s_keys[sub][pos] = (((unsigned long long)kb) << 32) | (unsigned)g;
            }
        }
    }
    __syncthreads();

    const int grp = tid >> 8;      // sub-slice group
    const int p = tid & 255;       // pixel within tile
    int cb = min(s_cnt[grp], CAP);
    int maxcb = max(max(min(s_cnt[0],CAP), min(s_cnt[1],CAP)),
                    max(min(s_cnt[2],CAP), min(s_cnt[3],CAP)));

    // Phase B: rank sort per sub-slice (unique keys => stable argsort)
    for (int s = p; s < cb; s += 256) {
        unsigned long long my = s_keys[grp][s];
        int r = 0;
        for (int j = 0; j < cb; ++j) r += (s_keys[grp][j] < my);
        s_sorted[grp][r] = (unsigned)(my & 0xffffffffu);
    }
    __syncthreads();

    // Phase C: blend (uniform rounds; wave-uniform early-out)
    const int pxi = p & 15, pyi = p >> 4;
    const float px = (float)(w + pxi), py = (float)(h + pyi);
    float T = 1.0f, acR = 0.f, acG = 0.f, acB = 0.f, acD = 0.f, acA = 0.f;

    const int rounds = (maxcb + 255) >> 8;
    for (int r = 0; r < rounds; ++r) {
        int base = r << 8;
        int m = cb - base; m = m < 0 ? 0 : (m > 256 ? 256 : m);
        if (r) __syncthreads();
        if (p < m) {
            int g = (int)s_sorted[grp][base + p];
            sA[grp][p] = A[g]; sBp[grp][p] = Bp[g];
        }
        __syncthreads();
        for (int jj = 0; jj < m; ++jj) {
            float4 a4 = sA[grp][jj];
            float ddx = px - a4.x, ddy = py - a4.y;
            float4 bp = sBp[grp][jj];
            float power = -0.5f * (ddx*ddx*a4.z + ddy*ddy*a4.w + ddx*ddy*bp.x);
            if (__any(power > -14.0f)) {   // skipped: alpha < 1e-6
                unsigned rg = __float_as_uint(bp.z), bd = __float_as_uint(bp.w);
                float c_r = __half2float(__ushort_as_half((unsigned short)(rg & 0xffff)));
                float c_g = __half2float(__ushort_as_half((unsigned short)(rg >> 16)));
                float c_b = __half2float(__ushort_as_half((unsigned short)(bd & 0xffff)));
                float dpv = __half2float(__ushort_as_half((unsigned short)(bd >> 16)));
                float alpha = fminf(__expf(power) * bp.y, 0.99f);
                float wgt = alpha * T;
                acR += wgt * c_r; acG += wgt * c_g; acB += wgt * c_b;
                acD += wgt * dpv; acA += wgt;
                T *= (1.0f - alpha);
            }
        }
    }

    // Phase D: in-block ordered combine of 4 sub-slices -> macro partial
    __syncthreads();
    s_part[grp][p][0] = acR; s_part[grp][p][1] = acG; s_part[grp][p][2] = acB;
    s_part[grp][p][3] = acD; s_part[grp][p][4] = acA; s_part[grp][p][5] = T;
    __syncthreads();
    if (grp == 0) {
        float Tpre = 1.0f, CR = 0.f, CG = 0.f, CB = 0.f, DP = 0.f, AC = 0.f;
#pragma unroll
        for (int s = 0; s < NSUB; ++s) {
            CR += Tpre * s_part[s][p][0];
            CG += Tpre * s_part[s][p][1];
            CB += Tpre * s_part[s][p][2];
            DP += Tpre * s_part[s][p][3];
            AC += Tpre * s_part[s][p][4];
            Tpre *= s_part[s][p][5];
        }
        const int idx = (mac * 64 + tile) * 256 + p;
        P1[idx] = make_float4(CR, CG, CB, DP);
        P2[idx] = make_float2(AC, Tpre);
    }
}

// 64 blocks x 256 thr: ordered combine of 4 macro-buckets + white background
__global__ __launch_bounds__(TPB) void gs_combine(
    const float4* __restrict__ P1, const float2* __restrict__ P2,
    float* __restrict__ out)
{
    const int tid = threadIdx.x;
    const int tile = blockIdx.x;
    const int h = (tile >> 3) * 16;
    const int w = (tile & 7) * 16;

    float Tpre = 1.0f, cr = 0.f, cg = 0.f, cb = 0.f, dp = 0.f, ac = 0.f;
#pragma unroll
    for (int s = 0; s < NMAC; ++s) {
        const int idx = (s * 64 + tile) * TPB + tid;
        float4 p1 = P1[idx];
        float2 p2 = P2[idx];
        cr += Tpre * p1.x; cg += Tpre * p1.y; cb += Tpre * p1.z;
        dp += Tpre * p1.w; ac += Tpre * p2.x;
        Tpre *= p2.y;
    }

    cr += (1.0f - ac); cg += (1.0f - ac); cb += (1.0f - ac);

    const int pxi = tid & 15, pyi = tid >> 4;
    const int y = h + pyi, x = w + pxi;
    const int pix = y * 128 + x;
    out[pix*3 + 0] = cr;
    out[pix*3 + 1] = cg;
    out[pix*3 + 2] = cb;
    out[128*128*3 + pix] = dp;
    out[128*128*3 + 128*128 + pix] = ac;
}

extern "C" void kernel_launch(void* const* d_in, const int* in_sizes, int n_in,
                              void* d_out, int out_size, void* d_ws, size_t ws_size,
                              hipStream_t stream) {
    const float* means3D    = (const float*)d_in[0];
    const float* opacity    = (const float*)d_in[1];
    const float* scales     = (const float*)d_in[2];
    const float* rotations  = (const float*)d_in[3];
    const float* shs        = (const float*)d_in[4];
    const float* viewmatrix = (const float*)d_in[5];
    const float* projmatrix = (const float*)d_in[6];
    const float* camcenter  = (const float*)d_in[7];
    float* out = (float*)d_out;

    int N = in_sizes[0] / 3;   // 8192
    int nblk = (N + TPB - 1) / TPB;

    char* p = (char*)d_ws;
    float4* A = (float4*)p;          p += (size_t)NMAX * sizeof(float4);
    float4* Bp = (float4*)p;         p += (size_t)NMAX * sizeof(float4);
    uint4* TMK = (uint4*)p;          p += (size_t)NMAX * sizeof(uint4);
    float4* P1 = (float4*)p;         p += (size_t)NMAC * 64 * TPB * sizeof(float4);
    float2* P2 = (float2*)p;         p += (size_t)NMAC * 64 * TPB * sizeof(float2);
    unsigned* MMpart = (unsigned*)p; p += (size_t)2 * nblk * sizeof(unsigned);

    gs_preprocess<<<nblk, TPB, 0, stream>>>(
        means3D, opacity, scales, rotations, shs, viewmatrix, projmatrix,
        camcenter, A, Bp, TMK, MMpart, N);

    gs_render<<<dim3(NMAC, 64), RTPB, 0, stream>>>(
        A, Bp, TMK, MMpart, P1, P2, N, nblk);

    gs_combine<<<64, TPB, 0, stream>>>(P1, P2, out);
}